// Round 5
// baseline (345.728 us; speedup 1.0000x reference)
//
#include <hip/hip_runtime.h>
#include <hip/hip_bf16.h>

typedef _Float16 f16;
typedef _Float16 f16x8 __attribute__((ext_vector_type(8)));
typedef float f32x4 __attribute__((ext_vector_type(4)));

#define BD 512     // D == H == 512
#define NBLK 512   // grid size; 2 blocks/CU x 256 CUs -> all co-resident

// async global->LDS, 16B per lane. LDS dest is wave-uniform base + lane*16.
__device__ __forceinline__ void llds16(const f16* g, f16* l) {
  __builtin_amdgcn_global_load_lds(
      (const __attribute__((address_space(1))) unsigned int*)g,
      (__attribute__((address_space(3))) unsigned int*)l,
      16, 0, 0);
}

// device-wide spin barrier; counter must be zero on entry (memset node each call).
// All NBLK blocks are co-resident by capacity arithmetic (LDS 72KB -> 2/CU).
__device__ __forceinline__ void gbar(unsigned int* c) {
  __threadfence();                    // release: drain stores, writeback L2
  __syncthreads();
  if (threadIdx.x == 0) {
    atomicAdd(c, 1u);
    while (atomicAdd(c, 0u) < NBLK) __builtin_amdgcn_s_sleep(2);
  }
  __syncthreads();
  __threadfence();                    // acquire: invalidate stale cache
}

__global__ __launch_bounds__(256, 2) void fused_all(
    const float* __restrict__ x, const float* __restrict__ memf,
    const float* __restrict__ logits,
    const float* __restrict__ projW, const float* __restrict__ projB,
    const float* __restrict__ opsW, const float* __restrict__ opsB,
    float* __restrict__ out,
    f16* __restrict__ xh, f16* __restrict__ g0, f16* __restrict__ wh,
    float* __restrict__ novPart, unsigned int* __restrict__ bars) {
  __shared__ __align__(16) char lds[3 * 24576];   // GEMM ring; phase-A overlay

  const int t = threadIdx.x, l = t & 63, w = t >> 6;
  const int bid = blockIdx.x;
  const int lr = l & 15, lk = l >> 4;

  // ---- routing: top-2 of 3 logits (softmax monotonic; ties -> lower idx) ----
  const float l0 = logits[0], l1 = logits[1], l2 = logits[2];
  int ia = 0; float ba = l0;
  if (l1 > ba) { ba = l1; ia = 1; }
  if (l2 > ba) { ba = l2; ia = 2; }
  int ib = 0; float bb2 = -3.4e38f;
  if (ia != 0)             { bb2 = l0; ib = 0; }
  if (ia != 1 && l1 > bb2) { bb2 = l1; ib = 1; }
  if (ia != 2 && l2 > bb2) { bb2 = l2; ib = 2; }

  // =================== phase A: weight cvt + x cvt + novelty ===================
  {
    f16*   xt  = (f16*)lds;               // 16 KB: block's 16 x-rows, swizzled
    float* xn  = (float*)(lds + 16384);   // 16 row sumsq
    float* red = xn + 16;                 // 4

    // weights: 1,048,576 f16 = 512 blocks * 256 thr * 8
    {
      const int e = (bid * 256 + t) * 8;
      const float* s = (e < 262144) ? (projW + e) : (opsW + (e - 262144));
      float4 v0 = ((const float4*)s)[0];
      float4 v1 = ((const float4*)s)[1];
      f16x8 h;
      h[0]=(f16)v0.x; h[1]=(f16)v0.y; h[2]=(f16)v0.z; h[3]=(f16)v0.w;
      h[4]=(f16)v1.x; h[5]=(f16)v1.y; h[6]=(f16)v1.z; h[7]=(f16)v1.w;
      *(f16x8*)&wh[e] = h;
    }

    // x: 16 rows per block; thread handles row t>>4, cols (t&15)*32..+31
    {
      const int r16 = t >> 4;
      const int cg  = t & 15;
      const size_t grow = (size_t)bid * 16 + r16;
      const float* src = x + grow * BD + cg * 32;
      float ss = 0.f;
      #pragma unroll
      for (int j = 0; j < 4; ++j) {
        float4 v0 = ((const float4*)src)[2 * j];
        float4 v1 = ((const float4*)src)[2 * j + 1];
        f16x8 h;
        h[0]=(f16)v0.x; h[1]=(f16)v0.y; h[2]=(f16)v0.z; h[3]=(f16)v0.w;
        h[4]=(f16)v1.x; h[5]=(f16)v1.y; h[6]=(f16)v1.z; h[7]=(f16)v1.w;
        *(f16x8*)&xh[grow * BD + cg * 32 + j * 8] = h;
        const int ch = cg * 4 + j;
        *(f16x8*)&xt[r16 * BD + ((ch ^ (r16 & 7)) << 3)] = h;
        ss += v0.x*v0.x + v0.y*v0.y + v0.z*v0.z + v0.w*v0.w
            + v1.x*v1.x + v1.y*v1.y + v1.z*v1.z + v1.w*v1.w;
      }
      #pragma unroll
      for (int off = 1; off < 16; off <<= 1) ss += __shfl_xor(ss, off, 64);
      if (cg == 0) xn[r16] = ss;
    }
    __syncthreads();

    // novelty: wave w covers mem rows w*16..+15 (f16 in regs), x rows 0..15
    const int mm = w * 16 + lr;
    f32x4 nacc = (f32x4){0.f, 0.f, 0.f, 0.f};
    float msq = 0.f;
    #pragma unroll
    for (int kk = 0; kk < BD; kk += 32) {
      f16x8 bfr;
      if (mm < 50) {
        const float* ms = memf + (size_t)mm * BD + kk + lk * 8;
        float4 v0 = ((const float4*)ms)[0];
        float4 v1 = ((const float4*)ms)[1];
        bfr[0]=(f16)v0.x; bfr[1]=(f16)v0.y; bfr[2]=(f16)v0.z; bfr[3]=(f16)v0.w;
        bfr[4]=(f16)v1.x; bfr[5]=(f16)v1.y; bfr[6]=(f16)v1.z; bfr[7]=(f16)v1.w;
        msq += v0.x*v0.x + v0.y*v0.y + v0.z*v0.z + v0.w*v0.w
             + v1.x*v1.x + v1.y*v1.y + v1.z*v1.z + v1.w*v1.w;
      } else {
        #pragma unroll
        for (int j = 0; j < 8; ++j) bfr[j] = (f16)0.f;
      }
      const int ch = (kk >> 3) + lk;
      f16x8 afr = *(const f16x8*)&xt[lr * BD + ((ch ^ (lr & 7)) << 3)];
      nacc = __builtin_amdgcn_mfma_f32_16x16x32_f16(afr, bfr, nacc, 0, 0, 0);
    }
    msq += __shfl_xor(msq, 16, 64);
    msq += __shfl_xor(msq, 32, 64);
    float local = 0.f;
    if (mm < 50) {
      #pragma unroll
      for (int j = 0; j < 4; ++j) {
        const int row = lk * 4 + j;          // C/D: row = (lane>>4)*4 + j
        float d = xn[row] - 2.f * nacc[j] + msq;
        local += sqrtf(fmaxf(d, 0.f));
      }
    }
    #pragma unroll
    for (int off = 32; off; off >>= 1) local += __shfl_down(local, off, 64);
    if (l == 0) red[w] = local;
    __syncthreads();
    if (t == 0) novPart[bid] = red[0] + red[1] + red[2] + red[3];
  }

  gbar(bars + 0);   // xh, wh, novPart visible device-wide

  // novelty final: block 0, wave 0 (everyone else proceeds to GEMM)
  if (bid == 0 && w == 0) {
    float s = 0.f;
    #pragma unroll
    for (int i = 0; i < 8; ++i) s += novPart[l + i * 64];
    #pragma unroll
    for (int off = 32; off; off >>= 1) s += __shfl_down(s, off, 64);
    if (l == 0) out[4194304] = fminf(1.5f, s * (1.0f / (8192.0f * 50.0f)));
  }

  // =================== GEMM layers: out = relu(A @ W^T + bias) ===================
  const int wr = w >> 1, wc = w & 1;      // wave tile: rows wr*32, cols wc*64
  const int rowBase = (bid >> 2) * 64;
  const int colBase = (bid & 3) * 128;

  auto gemm = [&](const f16* __restrict__ A, const f16* __restrict__ Wm,
                  const float* __restrict__ bias, void* Out, bool outf16) {
    f32x4 acc[2][4];
    #pragma unroll
    for (int m = 0; m < 2; ++m)
      #pragma unroll
      for (int n = 0; n < 4; ++n) acc[m][n] = (f32x4){0.f, 0.f, 0.f, 0.f};

    auto stage = [&](int buf, int kt) {
      f16* Ab = (f16*)(lds + buf * 24576);
      f16* Bb = (f16*)(lds + buf * 24576 + 8192);
      #pragma unroll
      for (int i = 0; i < 2; ++i) {
        const int o = i * 4096 + t * 16;     // byte offset in 8 KB A tile
        const int row = o >> 7;              // 128 B per row (64 f16)
        const int sch = ((o >> 4) & 7) ^ (row & 7);
        llds16(A + (size_t)(rowBase + row) * BD + kt + sch * 8,
               Ab + (i * 4096 + w * 1024) / 2);
      }
      #pragma unroll
      for (int i = 0; i < 4; ++i) {
        const int o = i * 4096 + t * 16;     // byte offset in 16 KB B tile
        const int row = o >> 7;
        const int sch = ((o >> 4) & 7) ^ (row & 7);
        llds16(Wm + (size_t)(colBase + row) * BD + kt + sch * 8,
               Bb + (i * 4096 + w * 1024) / 2);
      }
    };

    auto compute = [&](int buf) {
      const f16* Ab = (const f16*)(lds + buf * 24576);
      const f16* Bb = (const f16*)(lds + buf * 24576 + 8192);
      #pragma unroll
      for (int kk = 0; kk < 64; kk += 32) {
        f16x8 af[2], bf[4];
        #pragma unroll
        for (int m = 0; m < 2; ++m) {
          const int row = wr * 32 + m * 16 + lr;
          const int ch = (kk >> 3) + lk;
          af[m] = *(const f16x8*)&Ab[row * 64 + ((ch ^ (row & 7)) << 3)];
        }
        #pragma unroll
        for (int n = 0; n < 4; ++n) {
          const int row = wc * 64 + n * 16 + lr;
          const int ch = (kk >> 3) + lk;
          bf[n] = *(const f16x8*)&Bb[row * 64 + ((ch ^ (row & 7)) << 3)];
        }
        __builtin_amdgcn_s_setprio(1);
        #pragma unroll
        for (int m = 0; m < 2; ++m)
          #pragma unroll
          for (int n = 0; n < 4; ++n)
            acc[m][n] = __builtin_amdgcn_mfma_f32_16x16x32_f16(af[m], bf[n], acc[m][n], 0, 0, 0);
        __builtin_amdgcn_s_setprio(0);
      }
    };

    // 3-deep ring, one barrier per K-step, counted vmcnt (never 0 mid-loop)
    stage(0, 0);
    stage(1, 64);
    #pragma unroll
    for (int t8 = 0; t8 < 8; ++t8) {
      if (t8 < 7) asm volatile("s_waitcnt vmcnt(6)" ::: "memory");
      else        asm volatile("s_waitcnt vmcnt(0)" ::: "memory");
      __builtin_amdgcn_s_barrier();          // tile t8 fully in LDS (all waves)
      if (t8 < 6) stage((t8 + 2) % 3, (t8 + 2) * 64);
      compute(t8 % 3);
      asm volatile("s_waitcnt lgkmcnt(0)" ::: "memory");  // ds_reads drained
    }

    #pragma unroll
    for (int n = 0; n < 4; ++n) {
      const int col = colBase + wc * 64 + n * 16 + lr;
      const float bbv = bias[col];
      #pragma unroll
      for (int m = 0; m < 2; ++m) {
        #pragma unroll
        for (int j = 0; j < 4; ++j) {
          const int rowg = rowBase + wr * 32 + m * 16 + lk * 4 + j;
          float v = fmaxf(acc[m][n][j] + bbv, 0.f);
          if (outf16) ((f16*)Out)[(size_t)rowg * BD + col] = (f16)v;
          else        ((float*)Out)[(size_t)rowg * BD + col] = v;
        }
      }
    }
  };

  // layer 1: g0 = relu(xh @ projW^T + projB)
  gemm(xh, wh, projB, (void*)g0, true);
  gbar(bars + 1);
  // layer 2: h1 = relu(g0 @ Wa^T + ba)  (h1 reuses xh; WAR safe across barrier)
  gemm(g0, wh + 262144 + (size_t)ia * BD * BD, opsB + ia * BD, (void*)xh, true);
  gbar(bars + 2);
  // layer 3: out = relu(h1 @ Wb^T + bb)  (fp32 out)
  gemm(xh, wh + 262144 + (size_t)ib * BD * BD, opsB + ib * BD, (void*)out, false);
}

extern "C" void kernel_launch(void* const* d_in, const int* in_sizes, int n_in,
                              void* d_out, int out_size, void* d_ws, size_t ws_size,
                              hipStream_t stream) {
  const float* x      = (const float*)d_in[0];   // [8192,512]
  const float* memf   = (const float*)d_in[1];   // [50,512]
  const float* logits = (const float*)d_in[2];   // [3]
  const float* projW  = (const float*)d_in[3];   // [512,512]
  const float* projB  = (const float*)d_in[4];   // [512]
  const float* opsW   = (const float*)d_in[5];   // [3,512,512]
  const float* opsB   = (const float*)d_in[6];   // [3,512]
  float* out = (float*)d_out;                    // [8192*512 + 1]

  char* ws = (char*)d_ws;
  f16*   xh      = (f16*)(ws);               // 8 MB (x f16; reused as h1)
  f16*   g0      = (f16*)(ws + 8388608);     // 8 MB
  f16*   wh      = (f16*)(ws + 16777216);    // 2 MB: proj_W f16, then ops_W f16
  float* novPart = (float*)(ws + 18874368);  // 2 KB (512 floats)
  unsigned int* bars = (unsigned int*)(ws + 18878464);  // 3 counters

  hipMemsetAsync(bars, 0, 12, stream);       // graph memset node; runs every call

  void* args_unused = nullptr; (void)args_unused;
  fused_all<<<NBLK, 256, 0, stream>>>(x, memf, logits, projW, projB, opsW, opsB,
                                      out, xh, g0, wh, novPart, bars);
}

// Round 6
// 89.019 us; speedup vs baseline: 3.8838x; 3.8838x over previous
//
#include <hip/hip_runtime.h>
#include <hip/hip_bf16.h>

typedef _Float16 f16;
typedef _Float16 f16x8 __attribute__((ext_vector_type(8)));
typedef float f32x4 __attribute__((ext_vector_type(4)));

#define BD 512  // D == H == 512

// ---- prep: W fp32->f16 (1,048,576 elems) + zero novelty accumulators ----
__global__ __launch_bounds__(256) void prep_kernel(
    const float* __restrict__ projW, const float* __restrict__ opsW,
    f16* __restrict__ wh, float* __restrict__ novAcc,
    unsigned int* __restrict__ novCnt) {
  if (blockIdx.x == 0 && threadIdx.x == 0) { *novAcc = 0.f; *novCnt = 0u; }
  const int e = (blockIdx.x * 256 + threadIdx.x) * 32;
  const float* s = (e < 262144) ? (projW + e) : (opsW + (e - 262144));
  #pragma unroll
  for (int q = 0; q < 4; ++q) {
    float4 v0 = ((const float4*)s)[2 * q];
    float4 v1 = ((const float4*)s)[2 * q + 1];
    f16x8 h;
    h[0]=(f16)v0.x; h[1]=(f16)v0.y; h[2]=(f16)v0.z; h[3]=(f16)v0.w;
    h[4]=(f16)v1.x; h[5]=(f16)v1.y; h[6]=(f16)v1.z; h[7]=(f16)v1.w;
    *(f16x8*)&wh[e + q * 8] = h;
  }
}

// ---- mega: per block = 32 rows x ALL 512 cols, 3 layers chained in LDS ----
// 256 blocks x 512 threads (8 waves). Wave w owns cols w*64..+63.
// No cross-block deps after prep: activations live in LDS ping-pong panels.
__global__ __launch_bounds__(512, 2) void mega_kernel(
    const float* __restrict__ x, const float* __restrict__ memf,
    const float* __restrict__ logits, const f16* __restrict__ wh,
    const float* __restrict__ projB, const float* __restrict__ opsB,
    float* __restrict__ out, float* __restrict__ novAcc,
    unsigned int* __restrict__ novCnt) {
  __shared__ __align__(16) f16 act0[32 * BD];   // 32 KB, chunk-swizzled
  __shared__ __align__(16) f16 act1[32 * BD];   // 32 KB
  __shared__ float xn[32];

  const int t = threadIdx.x, l = t & 63, w = t >> 6;
  const int bid = blockIdx.x;
  const int lr = l & 15, lk = l >> 4;

  // ---- routing: top-2 of 3 logits (softmax monotonic; ties -> lower idx) ----
  const float l0 = logits[0], l1 = logits[1], l2 = logits[2];
  int ia = 0; float ba = l0;
  if (l1 > ba) { ba = l1; ia = 1; }
  if (l2 > ba) { ba = l2; ia = 2; }
  int ib = 0; float bb2 = -3.4e38f;
  if (ia != 0)             { bb2 = l0; ib = 0; }
  if (ia != 1 && l1 > bb2) { bb2 = l1; ib = 1; }
  if (ia != 2 && l2 > bb2) { bb2 = l2; ib = 2; }

  // ---- phase A: x fp32 -> f16 into swizzled LDS panel + row sumsq ----
  {
    const int r  = t >> 4;          // 0..31 (block-local row)
    const int cg = t & 15;          // 16 col-groups of 32 f32
    const float* src = x + ((size_t)bid * 32 + r) * BD + cg * 32;
    float ss = 0.f;
    #pragma unroll
    for (int j = 0; j < 4; ++j) {
      float4 v0 = ((const float4*)src)[2 * j];
      float4 v1 = ((const float4*)src)[2 * j + 1];
      f16x8 h;
      h[0]=(f16)v0.x; h[1]=(f16)v0.y; h[2]=(f16)v0.z; h[3]=(f16)v0.w;
      h[4]=(f16)v1.x; h[5]=(f16)v1.y; h[6]=(f16)v1.z; h[7]=(f16)v1.w;
      const int ch = cg * 4 + j;    // 16B chunk index 0..63
      *(f16x8*)&act0[r * BD + ((ch ^ (r & 7)) << 3)] = h;
      ss += v0.x*v0.x + v0.y*v0.y + v0.z*v0.z + v0.w*v0.w
          + v1.x*v1.x + v1.y*v1.y + v1.z*v1.z + v1.w*v1.w;
    }
    ss += __shfl_xor(ss, 1, 16); ss += __shfl_xor(ss, 2, 16);
    ss += __shfl_xor(ss, 4, 16); ss += __shfl_xor(ss, 8, 16);
    if (cg == 0) xn[r] = ss;
  }
  __syncthreads();

  // ---- novelty: waves 0..3 each take 16 mem rows; x panel from LDS ----
  if (w < 4) {
    const int mm = w * 16 + lr;
    f32x4 na0 = (f32x4){0.f,0.f,0.f,0.f};
    f32x4 na1 = (f32x4){0.f,0.f,0.f,0.f};
    float msq = 0.f;
    #pragma unroll 4
    for (int kk = 0; kk < BD; kk += 32) {
      f16x8 bfr;
      if (mm < 50) {
        const float* ms = memf + (size_t)mm * BD + kk + lk * 8;
        float4 v0 = ((const float4*)ms)[0];
        float4 v1 = ((const float4*)ms)[1];
        bfr[0]=(f16)v0.x; bfr[1]=(f16)v0.y; bfr[2]=(f16)v0.z; bfr[3]=(f16)v0.w;
        bfr[4]=(f16)v1.x; bfr[5]=(f16)v1.y; bfr[6]=(f16)v1.z; bfr[7]=(f16)v1.w;
        msq += v0.x*v0.x + v0.y*v0.y + v0.z*v0.z + v0.w*v0.w
             + v1.x*v1.x + v1.y*v1.y + v1.z*v1.z + v1.w*v1.w;
      } else {
        #pragma unroll
        for (int j = 0; j < 8; ++j) bfr[j] = (f16)0.f;
      }
      const int ch = (kk >> 3) + lk;
      f16x8 a0 = *(const f16x8*)&act0[lr * BD + ((ch ^ (lr & 7)) << 3)];
      na0 = __builtin_amdgcn_mfma_f32_16x16x32_f16(a0, bfr, na0, 0, 0, 0);
      f16x8 a1 = *(const f16x8*)&act0[(16 + lr) * BD + ((ch ^ (lr & 7)) << 3)];
      na1 = __builtin_amdgcn_mfma_f32_16x16x32_f16(a1, bfr, na1, 0, 0, 0);
    }
    msq += __shfl_xor(msq, 16, 64);
    msq += __shfl_xor(msq, 32, 64);
    float local = 0.f;
    if (mm < 50) {
      #pragma unroll
      for (int j = 0; j < 4; ++j) {
        const int r0 = lk * 4 + j;            // C/D: row = (lane>>4)*4 + j
        float d0 = xn[r0] - 2.f * na0[j] + msq;
        local += sqrtf(fmaxf(d0, 0.f));
        float d1 = xn[16 + r0] - 2.f * na1[j] + msq;
        local += sqrtf(fmaxf(d1, 0.f));
      }
    }
    #pragma unroll
    for (int off = 32; off; off >>= 1) local += __shfl_down(local, off, 64);
    if (l == 0) {
      atomicAdd(novAcc, local);
      __threadfence();
      const unsigned old = atomicAdd(novCnt, 1u);
      if (old == (gridDim.x << 2) - 1) {      // last of 4*256 wave-partials
        __threadfence();
        const float tot = atomicAdd(novAcc, 0.f);
        out[4194304] = fminf(1.5f, tot * (1.0f / (8192.0f * 50.0f)));
      }
    }
  }

  // ---- 3 layers: acc = actIn @ W^T; relu(+bias) -> actOut LDS / global ----
  const int wcol = w * 64;                    // wave's 64 output cols
  auto layer = [&](const f16* __restrict__ actIn, f16* __restrict__ actOut,
                   const f16* __restrict__ W, const float* __restrict__ bias,
                   bool toGlobal) {
    f32x4 acc[2][4];
    #pragma unroll
    for (int m = 0; m < 2; ++m)
      #pragma unroll
      for (int n = 0; n < 4; ++n) acc[m][n] = (f32x4){0.f,0.f,0.f,0.f};

    #pragma unroll 4
    for (int kk = 0; kk < BD; kk += 32) {
      const int ch = (kk >> 3) + lk;
      f16x8 af0 = *(const f16x8*)&actIn[lr * BD + ((ch ^ (lr & 7)) << 3)];
      f16x8 af1 = *(const f16x8*)&actIn[(16 + lr) * BD + ((ch ^ (lr & 7)) << 3)];
      f16x8 bf[4];
      #pragma unroll
      for (int n = 0; n < 4; ++n)
        bf[n] = *(const f16x8*)&W[(size_t)(wcol + n * 16 + lr) * BD + kk + lk * 8];
      #pragma unroll
      for (int n = 0; n < 4; ++n) {
        acc[0][n] = __builtin_amdgcn_mfma_f32_16x16x32_f16(af0, bf[n], acc[0][n], 0, 0, 0);
        acc[1][n] = __builtin_amdgcn_mfma_f32_16x16x32_f16(af1, bf[n], acc[1][n], 0, 0, 0);
      }
    }

    #pragma unroll
    for (int n = 0; n < 4; ++n) {
      const int colg = wcol + n * 16 + lr;
      const float bb = bias[colg];
      #pragma unroll
      for (int m = 0; m < 2; ++m) {
        #pragma unroll
        for (int j = 0; j < 4; ++j) {
          const int row = m * 16 + lk * 4 + j;
          const float v = fmaxf(acc[m][n][j] + bb, 0.f);
          if (toGlobal) {
            out[((size_t)bid * 32 + row) * BD + colg] = v;
          } else {
            const int ch2 = colg >> 3;
            actOut[row * BD + ((ch2 ^ (row & 7)) << 3) + (colg & 7)] = (f16)v;
          }
        }
      }
    }
    __syncthreads();   // actOut complete; all reads of actIn finished
  };

  layer(act0, act1, wh,                                   projB,        false);
  layer(act1, act0, wh + 262144 + (size_t)ia * 262144,    opsB + ia*BD, false);
  layer(act0, act1, wh + 262144 + (size_t)ib * 262144,    opsB + ib*BD, true);
}

extern "C" void kernel_launch(void* const* d_in, const int* in_sizes, int n_in,
                              void* d_out, int out_size, void* d_ws, size_t ws_size,
                              hipStream_t stream) {
  const float* x      = (const float*)d_in[0];   // [8192,512]
  const float* memf   = (const float*)d_in[1];   // [50,512]
  const float* logits = (const float*)d_in[2];   // [3]
  const float* projW  = (const float*)d_in[3];   // [512,512]
  const float* projB  = (const float*)d_in[4];   // [512]
  const float* opsW   = (const float*)d_in[5];   // [3,512,512]
  const float* opsB   = (const float*)d_in[6];   // [3,512]
  float* out = (float*)d_out;                    // [8192*512 + 1]

  char* ws = (char*)d_ws;
  f16*   wh     = (f16*)(ws);                 // 2 MB: proj_W f16, then ops_W f16
  float* novAcc = (float*)(ws + 2097152);     // 4 B
  unsigned int* novCnt = (unsigned int*)(ws + 2097156);  // 4 B

  prep_kernel<<<128, 256, 0, stream>>>(projW, opsW, wh, novAcc, novCnt);
  mega_kernel<<<256, 512, 0, stream>>>(x, memf, logits, wh, projB, opsB,
                                       out, novAcc, novCnt);
}